// Round 5
// baseline (1748.646 us; speedup 1.0000x reference)
//
#include <hip/hip_runtime.h>

#define N_NODES 100000
#define N_EDGES 3200000
static constexpr int NB = (N_NODES + 255) / 256;  // 391
// bucket partition: bucket = dst >> 8 (256 nodes per bucket)
#define NBUK 391   // ceil(N_NODES / 256)
#define NPB 256
#define CHUNK 8192
#define NCHUNK 391  // ceil(N_EDGES / CHUNK); 391*8192 = 3,203,072 >= 3.2M

__device__ __forceinline__ float bf2f(unsigned short u) {
  return __uint_as_float(((unsigned)u) << 16);
}
__device__ __forceinline__ unsigned short f2bf(float f) {
  unsigned u = __float_as_uint(f);
  u += 0x7fffu + ((u >> 16) & 1u);
  return (unsigned short)(u >> 16);
}
__device__ __forceinline__ float lo16(unsigned u) { return __uint_as_float(u << 16); }
__device__ __forceinline__ float hi16(unsigned u) { return __uint_as_float(u & 0xffff0000u); }

// ---------------- dtype detection (flag=1: bf16 storage, 0: fp32) ----------------

__global__ void k_detect(const unsigned short* __restrict__ xu, int* __restrict__ flag) {
  __shared__ int cnt;
  if (threadIdx.x == 0) cnt = 0;
  __syncthreads();
  int c = 0;
  for (int i = threadIdx.x; i < 4096; i += 256) {
    float v = fabsf(bf2f(xu[2 * i]));
    if (v >= 1e-4f && v <= 10.f) c++;
  }
  atomicAdd(&cnt, c);
  __syncthreads();
  if (threadIdx.x == 0) *flag = (cnt > 2048) ? 1 : 0;
}

// ---------------- canonicalize inputs to bf16 ----------------

__global__ __launch_bounds__(256) void k_cvt_x(const void* __restrict__ x,
                                               unsigned short* __restrict__ xb,
                                               const int* __restrict__ flag) {
  int i = blockIdx.x * 256 + threadIdx.x;  // one uint4 (8 bf16) per thread
  if (i >= N_NODES * 8) return;
  if (*flag) {
    ((uint4*)xb)[i] = ((const uint4*)x)[i];
  } else {
    const float4* xf = (const float4*)x;
    float4 a = xf[2 * i], b = xf[2 * i + 1];
    uint4 o;
    o.x = (unsigned)f2bf(a.x) | ((unsigned)f2bf(a.y) << 16);
    o.y = (unsigned)f2bf(a.z) | ((unsigned)f2bf(a.w) << 16);
    o.z = (unsigned)f2bf(b.x) | ((unsigned)f2bf(b.y) << 16);
    o.w = (unsigned)f2bf(b.z) | ((unsigned)f2bf(b.w) << 16);
    ((uint4*)xb)[i] = o;
  }
}

struct CvtArgs {
  const void* src[24];
  int dstoff[24];
  int n[24];
  int stride[24];
};

__global__ void k_cvt_w(CvtArgs a, unsigned short* __restrict__ wb,
                        const int* __restrict__ flag) {
  int b = blockIdx.x;
  const void* s = a.src[b];
  int n = a.n[b];
  int st = a.stride[b];
  unsigned short* d = wb + a.dstoff[b];
  int isbf = *flag;
  for (int i = threadIdx.x; i < n; i += 256)
    d[i * st] = isbf ? ((const unsigned short*)s)[i] : f2bf(((const float*)s)[i]);
}

// ---------------- CSR build: two-level bucket partition ----------------
// blist entry = (src << 8) | (dst & 255)  (src < 2^17, 25 bits total) ->
// half the partition write/read traffic vs uint2. counts is chunk-major so
// bhist/bscan/bscat all access it coalesced. Node offsets within a bucket
// are bbase[b] + LDS prefix, so degree/scan/fill fuse into one kernel.

// A1: per-chunk bucket histogram
__global__ __launch_bounds__(256) void k_bhist(const int* __restrict__ dsts,
                                               int* __restrict__ counts) {
  __shared__ int hist[NBUK];
  for (int i = threadIdx.x; i < NBUK; i += 256) hist[i] = 0;
  __syncthreads();
  int e0 = blockIdx.x * CHUNK;
  int n = min(CHUNK, N_EDGES - e0);
  for (int i = threadIdx.x; i < n; i += 256)
    atomicAdd(&hist[dsts[e0 + i] >> 8], 1);
  __syncthreads();
  for (int i = threadIdx.x; i < NBUK; i += 256)
    counts[blockIdx.x * NBUK + i] = hist[i];  // chunk-major
}

// A2: scan -> counts[c][b] becomes global write base; bbase[b] = bucket start
__global__ void k_bscan(int* __restrict__ counts, int* __restrict__ bbase) {
  __shared__ int tot[512];
  int t = threadIdx.x;
  int sum = 0;
  if (t < NBUK)
    for (int c = 0; c < NCHUNK; ++c) sum += counts[c * NBUK + t];
  tot[t] = sum;
  __syncthreads();
  for (int o = 1; o < 512; o <<= 1) {
    int u = (t >= o) ? tot[t - o] : 0;
    __syncthreads();
    tot[t] += u;
    __syncthreads();
  }
  int excl = tot[t] - sum;  // exclusive prefix (sum==0 for t>=NBUK)
  if (t <= NBUK) bbase[t] = excl;
  if (t < NBUK) {
    int run = excl;
    for (int c = 0; c < NCHUNK; ++c) {
      int v = counts[c * NBUK + t];
      counts[c * NBUK + t] = run;
      run += v;
    }
  }
}

// A3: rank-scatter packed (src<<8 | dst&255) into bucket-grouped list
__global__ __launch_bounds__(256) void k_bscat(const int* __restrict__ srcs,
                                               const int* __restrict__ dsts,
                                               const int* __restrict__ counts,
                                               unsigned* __restrict__ blist) {
  __shared__ int cnt[NBUK];
  for (int i = threadIdx.x; i < NBUK; i += 256)
    cnt[i] = counts[blockIdx.x * NBUK + i];
  __syncthreads();
  int e0 = blockIdx.x * CHUNK;
  int n = min(CHUNK, N_EDGES - e0);
  for (int i = threadIdx.x; i < n; i += 256) {
    int s = srcs[e0 + i];
    int d = dsts[e0 + i];
    int p = atomicAdd(&cnt[d >> 8], 1);
    blist[p] = ((unsigned)s << 8) | (unsigned)(d & 255);
  }
}

// B: fused per-bucket degree + scan + offset write + csr fill.
// Bucket b's nodes are contiguous, so off[node] = bbase[b] + LDS prefix.
__global__ __launch_bounds__(256) void k_bfinal(const unsigned* __restrict__ blist,
                                                const int* __restrict__ bbase,
                                                int* __restrict__ off,
                                                int* __restrict__ csr) {
  __shared__ int hcnt[NPB];
  __shared__ int sc[NPB];
  int t = threadIdx.x;
  int b = blockIdx.x;
  int s = bbase[b], e = bbase[b + 1];
  hcnt[t] = 0;
  __syncthreads();
  for (int i = s + t; i < e; i += 256)
    atomicAdd(&hcnt[blist[i] & 255], 1);
  __syncthreads();
  int v = hcnt[t];
  sc[t] = v;
  __syncthreads();
  for (int o = 1; o < 256; o <<= 1) {
    int u = (t >= o) ? sc[t - o] : 0;
    __syncthreads();
    sc[t] += u;
    __syncthreads();
  }
  int my = s + sc[t] - v;  // global csr offset of this node
  int node = b * NPB + t;
  if (node < N_NODES) off[node] = my;
  if (b == 0 && t == 0) off[N_NODES] = bbase[NBUK];
  sc[t] = my;  // becomes the scatter cursor
  __syncthreads();
  for (int i = s + t; i < e; i += 256) {
    unsigned u = blist[i];
    int p = atomicAdd(&sc[u & 255], 1);
    csr[p] = (int)(u >> 8);
  }
}

// ---------------- K,V projection: wave per row, packed Wk|Wv weights ----------------

__global__ __launch_bounds__(256) void k_gemmkv(
    const unsigned short* __restrict__ hin,
    const unsigned* __restrict__ PKV,  // lo=Wk, hi=Wv, [k*64+lane]
    const unsigned short* __restrict__ bk, const unsigned short* __restrict__ bv,
    unsigned short* __restrict__ Kt, unsigned short* __restrict__ Vt) {
  int r = blockIdx.x * 4 + (threadIdx.x >> 6);
  int lane = threadIdx.x & 63;
  float hv = bf2f(hin[(size_t)r * 64 + lane]);
  float ka = bf2f(bk[lane]);
  float va = bf2f(bv[lane]);
  for (int k = 0; k < 64; ++k) {
    float hk = __shfl(hv, k, 64);
    unsigned u = PKV[k * 64 + lane];
    ka += hk * lo16(u);
    va += hk * hi16(u);
  }
  Kt[(size_t)r * 64 + lane] = f2bf(ka);
  Vt[(size_t)r * 64 + lane] = f2bf(va);
}

// ---------------- edge pass, C=64 ----------------
// Round-3 structure (best measured: 249 µs @ 68 VGPR / 7 waves per SIMD),
// now with __launch_bounds__(256, 8) forcing VGPR<=64 -> 8 waves/SIMD.
// Occupancy proved the dominant lever (round 4: 92 VGPR / 5 waves -> 289 µs
// despite one fewer dependent memory round per batch).

template <bool RES>
__global__ __launch_bounds__(256, 8) void k_edge64(
    const int* __restrict__ off, const int* __restrict__ csr,
    const unsigned short* __restrict__ hin,
    const unsigned* __restrict__ PQS,  // lo=Wq, hi=Ws, [k*64+lane]
    const unsigned short* __restrict__ bq, const unsigned short* __restrict__ bs,
    const unsigned short* __restrict__ Kt, const unsigned short* __restrict__ Vt,
    unsigned short* __restrict__ hout) {
  __shared__ float qs[4][64];
  int w = threadIdx.x >> 6;
  int lane = threadIdx.x & 63;
  int wid = blockIdx.x * 4 + w;
  int base = off[wid];
  int deg = off[wid + 1] - base;
  // prefetch batch-0 src indices (overlaps csr load latency with projection)
  int nsrc = csr[base + ((lane < deg) ? lane : 0)];
  float hv = bf2f(hin[(size_t)wid * 64 + lane]);
  // projection: q_l, s_l (dim-per-lane, f32), packed weight loads
  float q = bf2f(bq[lane]);
  float sk = bf2f(bs[lane]);
  for (int k = 0; k < 64; ++k) {
    float hk = __shfl(hv, k, 64);
    unsigned uw = PQS[k * 64 + lane];
    q += hk * lo16(uw);
    sk += hk * hi16(uw);
  }
  qs[w][lane] = q;  // wave-local write->read; lgkmcnt ordering within wave

  float m = -1e30f, ssum = 0.f;
  float4 acc = {0.f, 0.f, 0.f, 0.f};
  int g = lane >> 4;    // edge subgroup in V phase
  int c16 = lane & 15;  // dim-quad index in V phase
  const float4* qv = (const float4*)qs[w];

  for (int j0 = 0; j0 < deg; j0 += 64) {
    int cnt = min(64, deg - j0);
    int src = nsrc;
    int nj = j0 + 64;
    if (nj < deg)  // prefetch next batch's src indices
      nsrc = csr[base + nj + ((lane < deg - nj) ? lane : 0)];
    // ---- phase 1: my edge's score ----
    const uint4* kp = (const uint4*)(Kt + (size_t)src * 64);
    float d0 = 0.f, d1 = 0.f, d2 = 0.f, d3 = 0.f;
#pragma unroll
    for (int i = 0; i < 8; ++i) {
      uint4 kk = kp[i];
      float4 qa = qv[2 * i];
      float4 qb = qv[2 * i + 1];
      d0 += qa.x * lo16(kk.x); d1 += qa.y * hi16(kk.x);
      d2 += qa.z * lo16(kk.y); d3 += qa.w * hi16(kk.y);
      d0 += qb.x * lo16(kk.z); d1 += qb.y * hi16(kk.z);
      d2 += qb.z * lo16(kk.w); d3 += qb.w * hi16(kk.w);
    }
    float sc = ((d0 + d1) + (d2 + d3)) * 0.125f;  // /sqrt(64)
    sc = fminf(fmaxf(sc, -60.f), 60.f);
    if (lane >= cnt) sc = -1e30f;
    // ---- batch softmax ----
    float bm = sc;
    bm = fmaxf(bm, __shfl_xor(bm, 32, 64));
    bm = fmaxf(bm, __shfl_xor(bm, 16, 64));
    bm = fmaxf(bm, __shfl_xor(bm, 8, 64));
    bm = fmaxf(bm, __shfl_xor(bm, 4, 64));
    bm = fmaxf(bm, __shfl_xor(bm, 2, 64));
    bm = fmaxf(bm, __shfl_xor(bm, 1, 64));
    float mn = fmaxf(m, bm);
    float al = __expf(sc - mn);  // inactive lanes -> 0
    float bsum = al;
    bsum += __shfl_xor(bsum, 32, 64);
    bsum += __shfl_xor(bsum, 16, 64);
    bsum += __shfl_xor(bsum, 8, 64);
    bsum += __shfl_xor(bsum, 4, 64);
    bsum += __shfl_xor(bsum, 2, 64);
    bsum += __shfl_xor(bsum, 1, 64);
    float corr = __expf(m - mn);
    ssum = ssum * corr + bsum;
    acc.x *= corr;
    acc.y *= corr;
    acc.z *= corr;
    acc.w *= corr;
    m = mn;
    // ---- phase 2: 4 edges per load, 16 edges (4 loads) in flight ----
    for (int jj = 0; jj < cnt; jj += 16) {
      int e0 = jj + g, e1 = jj + 4 + g, e2 = jj + 8 + g, e3 = jj + 12 + g;
      int s0 = __shfl(src, e0, 64);
      int s1 = __shfl(src, e1, 64);
      int s2 = __shfl(src, e2, 64);
      int s3 = __shfl(src, e3, 64);
      float a0 = __shfl(al, e0, 64);
      float a1 = __shfl(al, e1, 64);
      float a2 = __shfl(al, e2, 64);
      float a3 = __shfl(al, e3, 64);
      uint2 v0 = *(const uint2*)(Vt + (size_t)s0 * 64 + c16 * 4);
      uint2 v1 = *(const uint2*)(Vt + (size_t)s1 * 64 + c16 * 4);
      uint2 v2 = *(const uint2*)(Vt + (size_t)s2 * 64 + c16 * 4);
      uint2 v3 = *(const uint2*)(Vt + (size_t)s3 * 64 + c16 * 4);
      acc.x += a0 * lo16(v0.x); acc.y += a0 * hi16(v0.x);
      acc.z += a0 * lo16(v0.y); acc.w += a0 * hi16(v0.y);
      acc.x += a1 * lo16(v1.x); acc.y += a1 * hi16(v1.x);
      acc.z += a1 * lo16(v1.y); acc.w += a1 * hi16(v1.y);
      acc.x += a2 * lo16(v2.x); acc.y += a2 * hi16(v2.x);
      acc.z += a2 * lo16(v2.y); acc.w += a2 * hi16(v2.y);
      acc.x += a3 * lo16(v3.x); acc.y += a3 * hi16(v3.x);
      acc.z += a3 * lo16(v3.y); acc.w += a3 * hi16(v3.y);
    }
  }
  // combine the 4 edge-groups (lanes l, l^16, l^32, l^48 share dim-quad c16)
  acc.x += __shfl_xor(acc.x, 16, 64);
  acc.y += __shfl_xor(acc.y, 16, 64);
  acc.z += __shfl_xor(acc.z, 16, 64);
  acc.w += __shfl_xor(acc.w, 16, 64);
  acc.x += __shfl_xor(acc.x, 32, 64);
  acc.y += __shfl_xor(acc.y, 32, 64);
  acc.z += __shfl_xor(acc.z, 32, 64);
  acc.w += __shfl_xor(acc.w, 32, 64);
  // redistribute: lane l needs dim l = component (l&3) of quad at lane l>>2
  float f0 = __shfl(acc.x, lane >> 2, 64);
  float f1 = __shfl(acc.y, lane >> 2, 64);
  float f2 = __shfl(acc.z, lane >> 2, 64);
  float f3 = __shfl(acc.w, lane >> 2, 64);
  int cc = lane & 3;
  float aggv = (cc == 0) ? f0 : ((cc == 1) ? f1 : ((cc == 2) ? f2 : f3));
  float val = aggv / (ssum + 1e-16f) + sk;
  if (RES) val += hv;
  hout[(size_t)wid * 64 + lane] = f2bf(tanhf(val));
}

// ---------------- layer 3 projections (C=3): wave per node ----------------

__global__ __launch_bounds__(256) void k_gemm3(
    const unsigned short* __restrict__ hin,
    const unsigned short* __restrict__ Wq, const unsigned short* __restrict__ bq,
    const unsigned short* __restrict__ Wk, const unsigned short* __restrict__ bk,
    const unsigned short* __restrict__ Wv, const unsigned short* __restrict__ bv,
    const unsigned short* __restrict__ Ws, const unsigned short* __restrict__ bs,
    float* __restrict__ Q3, float* __restrict__ S3, uint4* __restrict__ KV3) {
  int r = blockIdx.x * 4 + (threadIdx.x >> 6);
  int lane = threadIdx.x & 63;
  float hj = bf2f(hin[(size_t)r * 64 + lane]);
  float p[12];
#pragma unroll
  for (int c = 0; c < 3; ++c) {
    p[c]     = hj * bf2f(Wq[lane * 3 + c]);
    p[3 + c] = hj * bf2f(Wk[lane * 3 + c]);
    p[6 + c] = hj * bf2f(Wv[lane * 3 + c]);
    p[9 + c] = hj * bf2f(Ws[lane * 3 + c]);
  }
#pragma unroll
  for (int o = 32; o >= 1; o >>= 1) {
#pragma unroll
    for (int i = 0; i < 12; ++i) p[i] += __shfl_xor(p[i], o, 64);
  }
  if (lane == 0) {
    float kk[3], vv[3];
    for (int c = 0; c < 3; ++c) {
      Q3[r * 4 + c] = p[c] + bf2f(bq[c]);
      S3[r * 4 + c] = p[9 + c] + bf2f(bs[c]);
      kk[c] = p[3 + c] + bf2f(bk[c]);
      vv[c] = p[6 + c] + bf2f(bv[c]);
    }
    uint4 pk;
    pk.x = (unsigned)f2bf(kk[0]) | ((unsigned)f2bf(vv[0]) << 16);
    pk.y = (unsigned)f2bf(kk[1]) | ((unsigned)f2bf(vv[1]) << 16);
    pk.z = (unsigned)f2bf(kk[2]) | ((unsigned)f2bf(vv[2]) << 16);
    pk.w = 0;
    KV3[r] = pk;
  }
}

// ---------------- edge pass, C=3: wave per dst (lane-per-edge) ----------------

__global__ __launch_bounds__(256) void k_edge3(
    const int* __restrict__ off, const int* __restrict__ csr,
    const float* __restrict__ Q3, const float* __restrict__ S3,
    const uint4* __restrict__ KV3, const void* __restrict__ noise,
    void* __restrict__ out, const int* __restrict__ flag) {
  int w = threadIdx.x >> 6;
  int lane = threadIdx.x & 63;
  int d = blockIdx.x * 4 + w;
  int base = off[d];
  int deg = off[d + 1] - base;
  float q0 = Q3[d * 4], q1 = Q3[d * 4 + 1], q2 = Q3[d * 4 + 2];
  const float isq = 0.57735026919f;  // 1/sqrt(3)
  float m = -1e30f, ssum = 0.f, a0 = 0.f, a1 = 0.f, a2 = 0.f;
  for (int j0 = 0; j0 < deg; j0 += 64) {
    int cnt = min(64, deg - j0);
    int src = csr[base + ((lane < cnt) ? (j0 + lane) : 0)];
    uint4 kv = KV3[src];
    float sc = (q0 * lo16(kv.x) + q1 * lo16(kv.y) + q2 * lo16(kv.z)) * isq;
    sc = fminf(fmaxf(sc, -60.f), 60.f);
    if (lane >= cnt) sc = -1e30f;
    float bm = sc;
#pragma unroll
    for (int o = 32; o >= 1; o >>= 1) bm = fmaxf(bm, __shfl_xor(bm, o, 64));
    float mn = fmaxf(m, bm);
    float al = __expf(sc - mn);  // inactive lanes -> 0
    float p0 = al * hi16(kv.x);
    float p1 = al * hi16(kv.y);
    float p2 = al * hi16(kv.z);
    float bsum = al;
#pragma unroll
    for (int o = 32; o >= 1; o >>= 1) {
      bsum += __shfl_xor(bsum, o, 64);
      p0 += __shfl_xor(p0, o, 64);
      p1 += __shfl_xor(p1, o, 64);
      p2 += __shfl_xor(p2, o, 64);
    }
    float corr = __expf(m - mn);
    ssum = ssum * corr + bsum;
    a0 = a0 * corr + p0;
    a1 = a1 * corr + p1;
    a2 = a2 * corr + p2;
    m = mn;
  }
  if (lane == 0) {
    float inv = 1.f / (ssum + 1e-16f);
    int isbf = *flag;
    float n0, n1, n2;
    if (isbf) {
      const unsigned short* nu = (const unsigned short*)noise;
      n0 = bf2f(nu[d * 3 + 0]);
      n1 = bf2f(nu[d * 3 + 1]);
      n2 = bf2f(nu[d * 3 + 2]);
    } else {
      const float* nf = (const float*)noise;
      n0 = nf[d * 3 + 0];
      n1 = nf[d * 3 + 1];
      n2 = nf[d * 3 + 2];
    }
    float r0 = a0 * inv + S3[d * 4 + 0] + 0.1f * n0;
    float r1 = a1 * inv + S3[d * 4 + 1] + 0.1f * n1;
    float r2 = a2 * inv + S3[d * 4 + 2] + 0.1f * n2;
    if (isbf) {
      unsigned short* ou = (unsigned short*)out;
      ou[d * 3 + 0] = f2bf(r0);
      ou[d * 3 + 1] = f2bf(r1);
      ou[d * 3 + 2] = f2bf(r2);
    } else {
      float* of = (float*)out;
      of[d * 3 + 0] = r0;
      of[d * 3 + 1] = r1;
      of[d * 3 + 2] = r2;
    }
  }
}

// ---------------- launch ----------------

extern "C" void kernel_launch(void* const* d_in, const int* in_sizes, int n_in,
                              void* d_out, int out_size, void* d_ws, size_t ws_size,
                              hipStream_t stream) {
  const int* ei = (const int*)d_in[1];
  const int* srcs = ei;
  const int* dsts = ei + N_EDGES;

  // Workspace (NEED = 51668480 B):
  //   off @0 | csr @400128 | h @13200128 (bf16; doubles as CSR-build scratch:
  //     counts @+524288 (NCHUNK*NBUK ints), bbase @+1200128 -- overwritten by
  //     k_cvt_x afterwards)
  //   kvbase @26000128: blist uint[3.2M] during build (12.8MB);
  //     then Kt bf16 @+0, Vt bf16 @+12800000; Q3/S3/KV3 in layer 3
  //   wb @51600128 | flag @51668352
  char* w = (char*)d_ws;
  int* off = (int*)w;
  int* csr = (int*)(w + 400128);
  char* hreg = w + 13200128;
  unsigned short* h = (unsigned short*)hreg;
  int* counts = (int*)(hreg + 524288);   // NCHUNK*NBUK ints = 611,524 B
  int* bbase = (int*)(hreg + 1200128);   // NBUK+1 ints
  char* kvbase = w + 26000128;
  unsigned* blist = (unsigned*)kvbase;
  unsigned short* Kt = (unsigned short*)kvbase;
  unsigned short* Vt = (unsigned short*)(kvbase + 12800000);
  float* Q3 = (float*)kvbase;
  float* S3 = (float*)(kvbase + 2097152);
  uint4* KV3 = (uint4*)(kvbase + 4194304);
  unsigned short* wb = (unsigned short*)(w + 51600128);
  int* flag = (int*)(w + 51668352);
  const size_t NEED = 51668480;
  if (ws_size < NEED) return;

  CvtArgs ca;
  {
    int idx = 0;
    const int moff[4] = {0, 8192, 8193, 1};  // q,k,v,s matrix dst offsets (shorts)
    const int boff[4] = {16384, 16448, 16512, 16576};
    for (int l = 0; l < 2; ++l) {
      int base = l * 16640;
      for (int p = 0; p < 4; ++p) {
        ca.src[idx] = d_in[3 + l * 8 + p * 2];
        ca.dstoff[idx] = base + moff[p];
        ca.n[idx] = 4096;
        ca.stride[idx] = 2;
        idx++;
        ca.src[idx] = d_in[3 + l * 8 + p * 2 + 1];
        ca.dstoff[idx] = base + boff[p];
        ca.n[idx] = 64;
        ca.stride[idx] = 1;
        idx++;
      }
    }
    int o = 33280;  // layer 3, stride-1
    for (int p = 0; p < 4; ++p) {
      ca.src[idx] = d_in[3 + 16 + p * 2];
      ca.dstoff[idx] = o;
      ca.n[idx] = 192;
      ca.stride[idx] = 1;
      o += 192;
      idx++;
      ca.src[idx] = d_in[3 + 16 + p * 2 + 1];
      ca.dstoff[idx] = o;
      ca.n[idx] = 3;
      ca.stride[idx] = 1;
      o += 3;
      idx++;
    }
  }
  const unsigned* PQS0 = (const unsigned*)(wb);
  const unsigned* PKV0 = (const unsigned*)(wb + 8192);
  const unsigned* PQS1 = (const unsigned*)(wb + 16640);
  const unsigned* PKV1 = (const unsigned*)(wb + 16640 + 8192);
  const unsigned short* Bq0 = wb + 16384;
  const unsigned short* Bk0 = wb + 16448;
  const unsigned short* Bv0 = wb + 16512;
  const unsigned short* Bs0 = wb + 16576;
  const unsigned short* Bq1 = wb + 16640 + 16384;
  const unsigned short* Bk1 = wb + 16640 + 16448;
  const unsigned short* Bv1 = wb + 16640 + 16512;
  const unsigned short* Bs1 = wb + 16640 + 16576;
  const unsigned short* W3q = wb + 33280;
  const unsigned short* B3q = wb + 33472;
  const unsigned short* W3k = wb + 33475;
  const unsigned short* B3k = wb + 33667;
  const unsigned short* W3v = wb + 33670;
  const unsigned short* B3v = wb + 33862;
  const unsigned short* W3s = wb + 33865;
  const unsigned short* B3s = wb + 34057;

  k_detect<<<1, 256, 0, stream>>>((const unsigned short*)d_in[0], flag);
  k_cvt_w<<<24, 256, 0, stream>>>(ca, wb, flag);

  // CSR build (uses hreg + kvbase as scratch; must precede k_cvt_x)
  k_bhist<<<NCHUNK, 256, 0, stream>>>(dsts, counts);
  k_bscan<<<1, 512, 0, stream>>>(counts, bbase);
  k_bscat<<<NCHUNK, 256, 0, stream>>>(srcs, dsts, counts, blist);
  k_bfinal<<<NBUK, 256, 0, stream>>>(blist, bbase, off, csr);

  k_cvt_x<<<N_NODES * 8 / 256, 256, 0, stream>>>(d_in[0], h, flag);

  const int gw = N_NODES / 4;  // 25000 blocks x 4 waves
  // layer 1
  k_gemmkv<<<gw, 256, 0, stream>>>(h, PKV0, Bk0, Bv0, Kt, Vt);
  k_edge64<false><<<gw, 256, 0, stream>>>(off, csr, h, PQS0, Bq0, Bs0, Kt, Vt, h);
  // layer 2
  k_gemmkv<<<gw, 256, 0, stream>>>(h, PKV1, Bk1, Bv1, Kt, Vt);
  k_edge64<true><<<gw, 256, 0, stream>>>(off, csr, h, PQS1, Bq1, Bs1, Kt, Vt, h);
  // layer 3
  k_gemm3<<<gw, 256, 0, stream>>>(h, W3q, B3q, W3k, B3k, W3v, B3v, W3s, B3s,
                                  Q3, S3, KV3);
  k_edge3<<<gw, 256, 0, stream>>>(off, csr, Q3, S3, KV3, d_in[2], d_out, flag);
}

// Round 6
// 900.929 us; speedup vs baseline: 1.9409x; 1.9409x over previous
//
#include <hip/hip_runtime.h>

#define N_NODES 100000
#define N_EDGES 3200000
static constexpr int NB = (N_NODES + 255) / 256;  // 391
// bucket partition: bucket = dst >> 8 (256 nodes per bucket)
#define NBUK 391   // ceil(N_NODES / 256)
#define NPB 256
#define CHUNK 8192
#define NCHUNK 391  // ceil(N_EDGES / CHUNK); 391*8192 = 3,203,072 >= 3.2M

__device__ __forceinline__ float bf2f(unsigned short u) {
  return __uint_as_float(((unsigned)u) << 16);
}
__device__ __forceinline__ unsigned short f2bf(float f) {
  unsigned u = __float_as_uint(f);
  u += 0x7fffu + ((u >> 16) & 1u);
  return (unsigned short)(u >> 16);
}
__device__ __forceinline__ float lo16(unsigned u) { return __uint_as_float(u << 16); }
__device__ __forceinline__ float hi16(unsigned u) { return __uint_as_float(u & 0xffff0000u); }

// ---------------- dtype detection (flag=1: bf16 storage, 0: fp32) ----------------

__global__ void k_detect(const unsigned short* __restrict__ xu, int* __restrict__ flag) {
  __shared__ int cnt;
  if (threadIdx.x == 0) cnt = 0;
  __syncthreads();
  int c = 0;
  for (int i = threadIdx.x; i < 4096; i += 256) {
    float v = fabsf(bf2f(xu[2 * i]));
    if (v >= 1e-4f && v <= 10.f) c++;
  }
  atomicAdd(&cnt, c);
  __syncthreads();
  if (threadIdx.x == 0) *flag = (cnt > 2048) ? 1 : 0;
}

// ---------------- canonicalize inputs to bf16 ----------------

__global__ __launch_bounds__(256) void k_cvt_x(const void* __restrict__ x,
                                               unsigned short* __restrict__ xb,
                                               const int* __restrict__ flag) {
  int i = blockIdx.x * 256 + threadIdx.x;  // one uint4 (8 bf16) per thread
  if (i >= N_NODES * 8) return;
  if (*flag) {
    ((uint4*)xb)[i] = ((const uint4*)x)[i];
  } else {
    const float4* xf = (const float4*)x;
    float4 a = xf[2 * i], b = xf[2 * i + 1];
    uint4 o;
    o.x = (unsigned)f2bf(a.x) | ((unsigned)f2bf(a.y) << 16);
    o.y = (unsigned)f2bf(a.z) | ((unsigned)f2bf(a.w) << 16);
    o.z = (unsigned)f2bf(b.x) | ((unsigned)f2bf(b.y) << 16);
    o.w = (unsigned)f2bf(b.z) | ((unsigned)f2bf(b.w) << 16);
    ((uint4*)xb)[i] = o;
  }
}

struct CvtArgs {
  const void* src[24];
  int dstoff[24];
  int n[24];
  int stride[24];
};

__global__ void k_cvt_w(CvtArgs a, unsigned short* __restrict__ wb,
                        const int* __restrict__ flag) {
  int b = blockIdx.x;
  const void* s = a.src[b];
  int n = a.n[b];
  int st = a.stride[b];
  unsigned short* d = wb + a.dstoff[b];
  int isbf = *flag;
  for (int i = threadIdx.x; i < n; i += 256)
    d[i * st] = isbf ? ((const unsigned short*)s)[i] : f2bf(((const float*)s)[i]);
}

// ---------------- CSR build: two-level bucket partition ----------------
// blist entry = (src << 8) | (dst & 255). counts chunk-major [c][b].
// Scan stage parallelized: per-bucket wave scan (391 one-wave blocks) +
// one-block bucket-total scan + coalesced base-add. (Old single-block
// serial-391-loop k_bscan was the only 1-CU serial step left.)

// A1: per-chunk bucket histogram
__global__ __launch_bounds__(256) void k_bhist(const int* __restrict__ dsts,
                                               int* __restrict__ counts) {
  __shared__ int hist[NBUK];
  for (int i = threadIdx.x; i < NBUK; i += 256) hist[i] = 0;
  __syncthreads();
  int e0 = blockIdx.x * CHUNK;
  int n = min(CHUNK, N_EDGES - e0);
  for (int i = threadIdx.x; i < n; i += 256)
    atomicAdd(&hist[dsts[e0 + i] >> 8], 1);
  __syncthreads();
  for (int i = threadIdx.x; i < NBUK; i += 256)
    counts[blockIdx.x * NBUK + i] = hist[i];  // chunk-major
}

// A2a: per-bucket exclusive prefix over chunks (one wave per bucket) + total
__global__ __launch_bounds__(64) void k_bscanA(int* __restrict__ counts,
                                               int* __restrict__ tot) {
  int b = blockIdx.x;
  int lane = threadIdx.x;
  int carry = 0;
  for (int c0 = 0; c0 < NCHUNK; c0 += 64) {
    int c = c0 + lane;
    int v = (c < NCHUNK) ? counts[c * NBUK + b] : 0;
    int s = v;
#pragma unroll
    for (int o = 1; o < 64; o <<= 1) {
      int u = __shfl_up(s, o, 64);
      if (lane >= o) s += u;
    }
    if (c < NCHUNK) counts[c * NBUK + b] = s - v + carry;  // bucket-local base
    carry += __shfl(s, 63, 64);
  }
  if (lane == 0) tot[b] = carry;
}

// A2b: scan bucket totals -> bbase
__global__ void k_bscanB(const int* __restrict__ tot, int* __restrict__ bbase) {
  __shared__ int s[512];
  int t = threadIdx.x;
  int v = (t < NBUK) ? tot[t] : 0;
  s[t] = v;
  __syncthreads();
  for (int o = 1; o < 512; o <<= 1) {
    int u = (t >= o) ? s[t - o] : 0;
    __syncthreads();
    s[t] += u;
    __syncthreads();
  }
  if (t <= NBUK) bbase[t] = s[t] - v;  // v==0 for t==NBUK -> total
}

// A2c: add bucket global base into per-chunk bases (coalesced)
__global__ void k_bscanC(int* __restrict__ counts, const int* __restrict__ bbase) {
  int t = threadIdx.x;
  if (t < NBUK) counts[blockIdx.x * NBUK + t] += bbase[t];
}

// A3: rank-scatter packed (src<<8 | dst&255) into bucket-grouped list
__global__ __launch_bounds__(256) void k_bscat(const int* __restrict__ srcs,
                                               const int* __restrict__ dsts,
                                               const int* __restrict__ counts,
                                               unsigned* __restrict__ blist) {
  __shared__ int cnt[NBUK];
  for (int i = threadIdx.x; i < NBUK; i += 256)
    cnt[i] = counts[blockIdx.x * NBUK + i];
  __syncthreads();
  int e0 = blockIdx.x * CHUNK;
  int n = min(CHUNK, N_EDGES - e0);
  for (int i = threadIdx.x; i < n; i += 256) {
    int s = srcs[e0 + i];
    int d = dsts[e0 + i];
    int p = atomicAdd(&cnt[d >> 8], 1);
    blist[p] = ((unsigned)s << 8) | (unsigned)(d & 255);
  }
}

// B: fused per-bucket degree + scan + offset write + csr fill.
// Bucket b's nodes are contiguous, so off[node] = bbase[b] + LDS prefix.
__global__ __launch_bounds__(256) void k_bfinal(const unsigned* __restrict__ blist,
                                                const int* __restrict__ bbase,
                                                int* __restrict__ off,
                                                int* __restrict__ csr) {
  __shared__ int hcnt[NPB];
  __shared__ int sc[NPB];
  int t = threadIdx.x;
  int b = blockIdx.x;
  int s = bbase[b], e = bbase[b + 1];
  hcnt[t] = 0;
  __syncthreads();
  for (int i = s + t; i < e; i += 256)
    atomicAdd(&hcnt[blist[i] & 255], 1);
  __syncthreads();
  int v = hcnt[t];
  sc[t] = v;
  __syncthreads();
  for (int o = 1; o < 256; o <<= 1) {
    int u = (t >= o) ? sc[t - o] : 0;
    __syncthreads();
    sc[t] += u;
    __syncthreads();
  }
  int my = s + sc[t] - v;  // global csr offset of this node
  int node = b * NPB + t;
  if (node < N_NODES) off[node] = my;
  if (b == 0 && t == 0) off[N_NODES] = bbase[NBUK];
  sc[t] = my;  // becomes the scatter cursor
  __syncthreads();
  for (int i = s + t; i < e; i += 256) {
    unsigned u = blist[i];
    int p = atomicAdd(&sc[u & 255], 1);
    csr[p] = (int)(u >> 8);
  }
}

// ---------------- K,V projection: wave per row, packed Wk|Wv weights ----------------

__global__ __launch_bounds__(256) void k_gemmkv(
    const unsigned short* __restrict__ hin,
    const unsigned* __restrict__ PKV,  // lo=Wk, hi=Wv, [k*64+lane]
    const unsigned short* __restrict__ bk, const unsigned short* __restrict__ bv,
    unsigned short* __restrict__ Kt, unsigned short* __restrict__ Vt) {
  int r = blockIdx.x * 4 + (threadIdx.x >> 6);
  int lane = threadIdx.x & 63;
  float hv = bf2f(hin[(size_t)r * 64 + lane]);
  float ka = bf2f(bk[lane]);
  float va = bf2f(bv[lane]);
  for (int k = 0; k < 64; ++k) {
    float hk = __shfl(hv, k, 64);
    unsigned u = PKV[k * 64 + lane];
    ka += hk * lo16(u);
    va += hk * hi16(u);
  }
  Kt[(size_t)r * 64 + lane] = f2bf(ka);
  Vt[(size_t)r * 64 + lane] = f2bf(va);
}

// ---------------- edge pass, C=64 ----------------
// EXACT round-3 body: best measured (249 µs @ 68 VGPR = 7 waves/SIMD).
// Measured VGPR/occupancy curve: 68->7 waves (249us), 92->5 (289us),
// forced bounds(256,8) -> 32 VGPR + full spill (622us). Do NOT add
// register pressure or min-waves bounds here.

template <bool RES>
__global__ __launch_bounds__(256) void k_edge64(
    const int* __restrict__ off, const int* __restrict__ csr,
    const unsigned short* __restrict__ hin,
    const unsigned* __restrict__ PQS,  // lo=Wq, hi=Ws, [k*64+lane]
    const unsigned short* __restrict__ bq, const unsigned short* __restrict__ bs,
    const unsigned short* __restrict__ Kt, const unsigned short* __restrict__ Vt,
    unsigned short* __restrict__ hout) {
  __shared__ float qs[4][64];
  int w = threadIdx.x >> 6;
  int lane = threadIdx.x & 63;
  int wid = blockIdx.x * 4 + w;
  int base = off[wid];
  int deg = off[wid + 1] - base;
  // prefetch batch-0 src indices (overlaps csr load latency with projection)
  int nsrc = csr[base + ((lane < deg) ? lane : 0)];
  float hv = bf2f(hin[(size_t)wid * 64 + lane]);
  // projection: q_l, s_l (dim-per-lane, f32), packed weight loads
  float q = bf2f(bq[lane]);
  float sk = bf2f(bs[lane]);
  for (int k = 0; k < 64; ++k) {
    float hk = __shfl(hv, k, 64);
    unsigned uw = PQS[k * 64 + lane];
    q += hk * lo16(uw);
    sk += hk * hi16(uw);
  }
  qs[w][lane] = q;  // wave-local write->read; lgkmcnt ordering within wave

  float m = -1e30f, ssum = 0.f;
  float4 acc = {0.f, 0.f, 0.f, 0.f};
  int g = lane >> 4;    // edge subgroup in V phase
  int c16 = lane & 15;  // dim-quad index in V phase
  const float4* qv = (const float4*)qs[w];

  for (int j0 = 0; j0 < deg; j0 += 64) {
    int cnt = min(64, deg - j0);
    int src = nsrc;
    int nj = j0 + 64;
    if (nj < deg)  // prefetch next batch's src indices
      nsrc = csr[base + nj + ((lane < deg - nj) ? lane : 0)];
    // ---- phase 1: my edge's score ----
    const uint4* kp = (const uint4*)(Kt + (size_t)src * 64);
    float d0 = 0.f, d1 = 0.f, d2 = 0.f, d3 = 0.f;
#pragma unroll
    for (int i = 0; i < 8; ++i) {
      uint4 kk = kp[i];
      float4 qa = qv[2 * i];
      float4 qb = qv[2 * i + 1];
      d0 += qa.x * lo16(kk.x); d1 += qa.y * hi16(kk.x);
      d2 += qa.z * lo16(kk.y); d3 += qa.w * hi16(kk.y);
      d0 += qb.x * lo16(kk.z); d1 += qb.y * hi16(kk.z);
      d2 += qb.z * lo16(kk.w); d3 += qb.w * hi16(kk.w);
    }
    float sc = ((d0 + d1) + (d2 + d3)) * 0.125f;  // /sqrt(64)
    sc = fminf(fmaxf(sc, -60.f), 60.f);
    if (lane >= cnt) sc = -1e30f;
    // ---- batch softmax ----
    float bm = sc;
    bm = fmaxf(bm, __shfl_xor(bm, 32, 64));
    bm = fmaxf(bm, __shfl_xor(bm, 16, 64));
    bm = fmaxf(bm, __shfl_xor(bm, 8, 64));
    bm = fmaxf(bm, __shfl_xor(bm, 4, 64));
    bm = fmaxf(bm, __shfl_xor(bm, 2, 64));
    bm = fmaxf(bm, __shfl_xor(bm, 1, 64));
    float mn = fmaxf(m, bm);
    float al = __expf(sc - mn);  // inactive lanes -> 0
    float bsum = al;
    bsum += __shfl_xor(bsum, 32, 64);
    bsum += __shfl_xor(bsum, 16, 64);
    bsum += __shfl_xor(bsum, 8, 64);
    bsum += __shfl_xor(bsum, 4, 64);
    bsum += __shfl_xor(bsum, 2, 64);
    bsum += __shfl_xor(bsum, 1, 64);
    float corr = __expf(m - mn);
    ssum = ssum * corr + bsum;
    acc.x *= corr;
    acc.y *= corr;
    acc.z *= corr;
    acc.w *= corr;
    m = mn;
    // ---- phase 2: 4 edges per load, 16 edges (4 loads) in flight ----
    for (int jj = 0; jj < cnt; jj += 16) {
      int e0 = jj + g, e1 = jj + 4 + g, e2 = jj + 8 + g, e3 = jj + 12 + g;
      int s0 = __shfl(src, e0, 64);
      int s1 = __shfl(src, e1, 64);
      int s2 = __shfl(src, e2, 64);
      int s3 = __shfl(src, e3, 64);
      float a0 = __shfl(al, e0, 64);
      float a1 = __shfl(al, e1, 64);
      float a2 = __shfl(al, e2, 64);
      float a3 = __shfl(al, e3, 64);
      uint2 v0 = *(const uint2*)(Vt + (size_t)s0 * 64 + c16 * 4);
      uint2 v1 = *(const uint2*)(Vt + (size_t)s1 * 64 + c16 * 4);
      uint2 v2 = *(const uint2*)(Vt + (size_t)s2 * 64 + c16 * 4);
      uint2 v3 = *(const uint2*)(Vt + (size_t)s3 * 64 + c16 * 4);
      acc.x += a0 * lo16(v0.x); acc.y += a0 * hi16(v0.x);
      acc.z += a0 * lo16(v0.y); acc.w += a0 * hi16(v0.y);
      acc.x += a1 * lo16(v1.x); acc.y += a1 * hi16(v1.x);
      acc.z += a1 * lo16(v1.y); acc.w += a1 * hi16(v1.y);
      acc.x += a2 * lo16(v2.x); acc.y += a2 * hi16(v2.x);
      acc.z += a2 * lo16(v2.y); acc.w += a2 * hi16(v2.y);
      acc.x += a3 * lo16(v3.x); acc.y += a3 * hi16(v3.x);
      acc.z += a3 * lo16(v3.y); acc.w += a3 * hi16(v3.y);
    }
  }
  // combine the 4 edge-groups (lanes l, l^16, l^32, l^48 share dim-quad c16)
  acc.x += __shfl_xor(acc.x, 16, 64);
  acc.y += __shfl_xor(acc.y, 16, 64);
  acc.z += __shfl_xor(acc.z, 16, 64);
  acc.w += __shfl_xor(acc.w, 16, 64);
  acc.x += __shfl_xor(acc.x, 32, 64);
  acc.y += __shfl_xor(acc.y, 32, 64);
  acc.z += __shfl_xor(acc.z, 32, 64);
  acc.w += __shfl_xor(acc.w, 32, 64);
  // redistribute: lane l needs dim l = component (l&3) of quad at lane l>>2
  float f0 = __shfl(acc.x, lane >> 2, 64);
  float f1 = __shfl(acc.y, lane >> 2, 64);
  float f2 = __shfl(acc.z, lane >> 2, 64);
  float f3 = __shfl(acc.w, lane >> 2, 64);
  int cc = lane & 3;
  float aggv = (cc == 0) ? f0 : ((cc == 1) ? f1 : ((cc == 2) ? f2 : f3));
  float val = aggv / (ssum + 1e-16f) + sk;
  if (RES) val += hv;
  hout[(size_t)wid * 64 + lane] = f2bf(tanhf(val));
}

// ---------------- layer 3 projections (C=3): wave per node ----------------

__global__ __launch_bounds__(256) void k_gemm3(
    const unsigned short* __restrict__ hin,
    const unsigned short* __restrict__ Wq, const unsigned short* __restrict__ bq,
    const unsigned short* __restrict__ Wk, const unsigned short* __restrict__ bk,
    const unsigned short* __restrict__ Wv, const unsigned short* __restrict__ bv,
    const unsigned short* __restrict__ Ws, const unsigned short* __restrict__ bs,
    float* __restrict__ Q3, float* __restrict__ S3, uint4* __restrict__ KV3) {
  int r = blockIdx.x * 4 + (threadIdx.x >> 6);
  int lane = threadIdx.x & 63;
  float hj = bf2f(hin[(size_t)r * 64 + lane]);
  float p[12];
#pragma unroll
  for (int c = 0; c < 3; ++c) {
    p[c]     = hj * bf2f(Wq[lane * 3 + c]);
    p[3 + c] = hj * bf2f(Wk[lane * 3 + c]);
    p[6 + c] = hj * bf2f(Wv[lane * 3 + c]);
    p[9 + c] = hj * bf2f(Ws[lane * 3 + c]);
  }
#pragma unroll
  for (int o = 32; o >= 1; o >>= 1) {
#pragma unroll
    for (int i = 0; i < 12; ++i) p[i] += __shfl_xor(p[i], o, 64);
  }
  if (lane == 0) {
    float kk[3], vv[3];
    for (int c = 0; c < 3; ++c) {
      Q3[r * 4 + c] = p[c] + bf2f(bq[c]);
      S3[r * 4 + c] = p[9 + c] + bf2f(bs[c]);
      kk[c] = p[3 + c] + bf2f(bk[c]);
      vv[c] = p[6 + c] + bf2f(bv[c]);
    }
    uint4 pk;
    pk.x = (unsigned)f2bf(kk[0]) | ((unsigned)f2bf(vv[0]) << 16);
    pk.y = (unsigned)f2bf(kk[1]) | ((unsigned)f2bf(vv[1]) << 16);
    pk.z = (unsigned)f2bf(kk[2]) | ((unsigned)f2bf(vv[2]) << 16);
    pk.w = 0;
    KV3[r] = pk;
  }
}

// ---------------- edge pass, C=3: wave per dst (lane-per-edge) ----------------

__global__ __launch_bounds__(256) void k_edge3(
    const int* __restrict__ off, const int* __restrict__ csr,
    const float* __restrict__ Q3, const float* __restrict__ S3,
    const uint4* __restrict__ KV3, const void* __restrict__ noise,
    void* __restrict__ out, const int* __restrict__ flag) {
  int w = threadIdx.x >> 6;
  int lane = threadIdx.x & 63;
  int d = blockIdx.x * 4 + w;
  int base = off[d];
  int deg = off[d + 1] - base;
  float q0 = Q3[d * 4], q1 = Q3[d * 4 + 1], q2 = Q3[d * 4 + 2];
  const float isq = 0.57735026919f;  // 1/sqrt(3)
  float m = -1e30f, ssum = 0.f, a0 = 0.f, a1 = 0.f, a2 = 0.f;
  for (int j0 = 0; j0 < deg; j0 += 64) {
    int cnt = min(64, deg - j0);
    int src = csr[base + ((lane < cnt) ? (j0 + lane) : 0)];
    uint4 kv = KV3[src];
    float sc = (q0 * lo16(kv.x) + q1 * lo16(kv.y) + q2 * lo16(kv.z)) * isq;
    sc = fminf(fmaxf(sc, -60.f), 60.f);
    if (lane >= cnt) sc = -1e30f;
    float bm = sc;
#pragma unroll
    for (int o = 32; o >= 1; o >>= 1) bm = fmaxf(bm, __shfl_xor(bm, o, 64));
    float mn = fmaxf(m, bm);
    float al = __expf(sc - mn);  // inactive lanes -> 0
    float p0 = al * hi16(kv.x);
    float p1 = al * hi16(kv.y);
    float p2 = al * hi16(kv.z);
    float bsum = al;
#pragma unroll
    for (int o = 32; o >= 1; o >>= 1) {
      bsum += __shfl_xor(bsum, o, 64);
      p0 += __shfl_xor(p0, o, 64);
      p1 += __shfl_xor(p1, o, 64);
      p2 += __shfl_xor(p2, o, 64);
    }
    float corr = __expf(m - mn);
    ssum = ssum * corr + bsum;
    a0 = a0 * corr + p0;
    a1 = a1 * corr + p1;
    a2 = a2 * corr + p2;
    m = mn;
  }
  if (lane == 0) {
    float inv = 1.f / (ssum + 1e-16f);
    int isbf = *flag;
    float n0, n1, n2;
    if (isbf) {
      const unsigned short* nu = (const unsigned short*)noise;
      n0 = bf2f(nu[d * 3 + 0]);
      n1 = bf2f(nu[d * 3 + 1]);
      n2 = bf2f(nu[d * 3 + 2]);
    } else {
      const float* nf = (const float*)noise;
      n0 = nf[d * 3 + 0];
      n1 = nf[d * 3 + 1];
      n2 = nf[d * 3 + 2];
    }
    float r0 = a0 * inv + S3[d * 4 + 0] + 0.1f * n0;
    float r1 = a1 * inv + S3[d * 4 + 1] + 0.1f * n1;
    float r2 = a2 * inv + S3[d * 4 + 2] + 0.1f * n2;
    if (isbf) {
      unsigned short* ou = (unsigned short*)out;
      ou[d * 3 + 0] = f2bf(r0);
      ou[d * 3 + 1] = f2bf(r1);
      ou[d * 3 + 2] = f2bf(r2);
    } else {
      float* of = (float*)out;
      of[d * 3 + 0] = r0;
      of[d * 3 + 1] = r1;
      of[d * 3 + 2] = r2;
    }
  }
}

// ---------------- launch ----------------

extern "C" void kernel_launch(void* const* d_in, const int* in_sizes, int n_in,
                              void* d_out, int out_size, void* d_ws, size_t ws_size,
                              hipStream_t stream) {
  const int* ei = (const int*)d_in[1];
  const int* srcs = ei;
  const int* dsts = ei + N_EDGES;

  // Workspace (NEED = 51668480 B):
  //   off @0 | csr @400128 | h @13200128 (bf16; doubles as CSR-build scratch:
  //     counts @+524288 (NCHUNK*NBUK ints), bbase @+1200128, tot @+1310720
  //     -- overwritten by k_cvt_x afterwards)
  //   kvbase @26000128: blist uint[3.2M] during build (12.8MB);
  //     then Kt bf16 @+0, Vt bf16 @+12800000; Q3/S3/KV3 in layer 3
  //   wb @51600128 | flag @51668352
  char* w = (char*)d_ws;
  int* off = (int*)w;
  int* csr = (int*)(w + 400128);
  char* hreg = w + 13200128;
  unsigned short* h = (unsigned short*)hreg;
  int* counts = (int*)(hreg + 524288);   // NCHUNK*NBUK ints = 611,524 B
  int* bbase = (int*)(hreg + 1200128);   // NBUK+1 ints
  int* tot = (int*)(hreg + 1310720);     // NBUK ints
  char* kvbase = w + 26000128;
  unsigned* blist = (unsigned*)kvbase;
  unsigned short* Kt = (unsigned short*)kvbase;
  unsigned short* Vt = (unsigned short*)(kvbase + 12800000);
  float* Q3 = (float*)kvbase;
  float* S3 = (float*)(kvbase + 2097152);
  uint4* KV3 = (uint4*)(kvbase + 4194304);
  unsigned short* wb = (unsigned short*)(w + 51600128);
  int* flag = (int*)(w + 51668352);
  const size_t NEED = 51668480;
  if (ws_size < NEED) return;

  CvtArgs ca;
  {
    int idx = 0;
    const int moff[4] = {0, 8192, 8193, 1};  // q,k,v,s matrix dst offsets (shorts)
    const int boff[4] = {16384, 16448, 16512, 16576};
    for (int l = 0; l < 2; ++l) {
      int base = l * 16640;
      for (int p = 0; p < 4; ++p) {
        ca.src[idx] = d_in[3 + l * 8 + p * 2];
        ca.dstoff[idx] = base + moff[p];
        ca.n[idx] = 4096;
        ca.stride[idx] = 2;
        idx++;
        ca.src[idx] = d_in[3 + l * 8 + p * 2 + 1];
        ca.dstoff[idx] = base + boff[p];
        ca.n[idx] = 64;
        ca.stride[idx] = 1;
        idx++;
      }
    }
    int o = 33280;  // layer 3, stride-1
    for (int p = 0; p < 4; ++p) {
      ca.src[idx] = d_in[3 + 16 + p * 2];
      ca.dstoff[idx] = o;
      ca.n[idx] = 192;
      ca.stride[idx] = 1;
      o += 192;
      idx++;
      ca.src[idx] = d_in[3 + 16 + p * 2 + 1];
      ca.dstoff[idx] = o;
      ca.n[idx] = 3;
      ca.stride[idx] = 1;
      o += 3;
      idx++;
    }
  }
  const unsigned* PQS0 = (const unsigned*)(wb);
  const unsigned* PKV0 = (const unsigned*)(wb + 8192);
  const unsigned* PQS1 = (const unsigned*)(wb + 16640);
  const unsigned* PKV1 = (const unsigned*)(wb + 16640 + 8192);
  const unsigned short* Bq0 = wb + 16384;
  const unsigned short* Bk0 = wb + 16448;
  const unsigned short* Bv0 = wb + 16512;
  const unsigned short* Bs0 = wb + 16576;
  const unsigned short* Bq1 = wb + 16640 + 16384;
  const unsigned short* Bk1 = wb + 16640 + 16448;
  const unsigned short* Bv1 = wb + 16640 + 16512;
  const unsigned short* Bs1 = wb + 16640 + 16576;
  const unsigned short* W3q = wb + 33280;
  const unsigned short* B3q = wb + 33472;
  const unsigned short* W3k = wb + 33475;
  const unsigned short* B3k = wb + 33667;
  const unsigned short* W3v = wb + 33670;
  const unsigned short* B3v = wb + 33862;
  const unsigned short* W3s = wb + 33865;
  const unsigned short* B3s = wb + 34057;

  k_detect<<<1, 256, 0, stream>>>((const unsigned short*)d_in[0], flag);
  k_cvt_w<<<24, 256, 0, stream>>>(ca, wb, flag);

  // CSR build (uses hreg + kvbase as scratch; must precede k_cvt_x)
  k_bhist<<<NCHUNK, 256, 0, stream>>>(dsts, counts);
  k_bscanA<<<NBUK, 64, 0, stream>>>(counts, tot);
  k_bscanB<<<1, 512, 0, stream>>>(tot, bbase);
  k_bscanC<<<NCHUNK, 512, 0, stream>>>(counts, bbase);
  k_bscat<<<NCHUNK, 256, 0, stream>>>(srcs, dsts, counts, blist);
  k_bfinal<<<NBUK, 256, 0, stream>>>(blist, bbase, off, csr);

  k_cvt_x<<<N_NODES * 8 / 256, 256, 0, stream>>>(d_in[0], h, flag);

  const int gw = N_NODES / 4;  // 25000 blocks x 4 waves
  // layer 1
  k_gemmkv<<<gw, 256, 0, stream>>>(h, PKV0, Bk0, Bv0, Kt, Vt);
  k_edge64<false><<<gw, 256, 0, stream>>>(off, csr, h, PQS0, Bq0, Bs0, Kt, Vt, h);
  // layer 2
  k_gemmkv<<<gw, 256, 0, stream>>>(h, PKV1, Bk1, Bv1, Kt, Vt);
  k_edge64<true><<<gw, 256, 0, stream>>>(off, csr, h, PQS1, Bq1, Bs1, Kt, Vt, h);
  // layer 3
  k_gemm3<<<gw, 256, 0, stream>>>(h, W3q, B3q, W3k, B3k, W3v, B3v, W3s, B3s,
                                  Q3, S3, KV3);
  k_edge3<<<gw, 256, 0, stream>>>(off, csr, Q3, S3, KV3, d_in[2], d_out, flag);
}

// Round 7
// 796.977 us; speedup vs baseline: 2.1941x; 1.1304x over previous
//
#include <hip/hip_runtime.h>

#define N_NODES 100000
#define N_EDGES 3200000
static constexpr int NB = (N_NODES + 255) / 256;  // 391
// bucket partition: bucket = dst >> 8 (256 nodes per bucket)
#define NBUK 391   // ceil(N_NODES / 256)
#define NPB 256
#define CHUNK 8192
#define NCHUNK 391  // ceil(N_EDGES / CHUNK); 391*8192 = 3,203,072 >= 3.2M

__device__ __forceinline__ float bf2f(unsigned short u) {
  return __uint_as_float(((unsigned)u) << 16);
}
__device__ __forceinline__ unsigned short f2bf(float f) {
  unsigned u = __float_as_uint(f);
  u += 0x7fffu + ((u >> 16) & 1u);
  return (unsigned short)(u >> 16);
}
__device__ __forceinline__ float lo16(unsigned u) { return __uint_as_float(u << 16); }
__device__ __forceinline__ float hi16(unsigned u) { return __uint_as_float(u & 0xffff0000u); }

// ---------------- dtype detection (flag=1: bf16 storage, 0: fp32) ----------------

__global__ void k_detect(const unsigned short* __restrict__ xu, int* __restrict__ flag) {
  __shared__ int cnt;
  if (threadIdx.x == 0) cnt = 0;
  __syncthreads();
  int c = 0;
  for (int i = threadIdx.x; i < 4096; i += 256) {
    float v = fabsf(bf2f(xu[2 * i]));
    if (v >= 1e-4f && v <= 10.f) c++;
  }
  atomicAdd(&cnt, c);
  __syncthreads();
  if (threadIdx.x == 0) *flag = (cnt > 2048) ? 1 : 0;
}

// ---------------- canonicalize inputs to bf16 ----------------

__global__ __launch_bounds__(256) void k_cvt_x(const void* __restrict__ x,
                                               unsigned short* __restrict__ xb,
                                               const int* __restrict__ flag) {
  int i = blockIdx.x * 256 + threadIdx.x;  // one uint4 (8 bf16) per thread
  if (i >= N_NODES * 8) return;
  if (*flag) {
    ((uint4*)xb)[i] = ((const uint4*)x)[i];
  } else {
    const float4* xf = (const float4*)x;
    float4 a = xf[2 * i], b = xf[2 * i + 1];
    uint4 o;
    o.x = (unsigned)f2bf(a.x) | ((unsigned)f2bf(a.y) << 16);
    o.y = (unsigned)f2bf(a.z) | ((unsigned)f2bf(a.w) << 16);
    o.z = (unsigned)f2bf(b.x) | ((unsigned)f2bf(b.y) << 16);
    o.w = (unsigned)f2bf(b.z) | ((unsigned)f2bf(b.w) << 16);
    ((uint4*)xb)[i] = o;
  }
}

struct CvtArgs {
  const void* src[24];
  int dstoff[24];
  int n[24];
  int stride[24];
};

__global__ void k_cvt_w(CvtArgs a, unsigned short* __restrict__ wb,
                        const int* __restrict__ flag) {
  int b = blockIdx.x;
  const void* s = a.src[b];
  int n = a.n[b];
  int st = a.stride[b];
  unsigned short* d = wb + a.dstoff[b];
  int isbf = *flag;
  for (int i = threadIdx.x; i < n; i += 256)
    d[i * st] = isbf ? ((const unsigned short*)s)[i] : f2bf(((const float*)s)[i]);
}

// ---------------- CSR build: two-level bucket partition ----------------

// A1: per-chunk bucket histogram
__global__ __launch_bounds__(256) void k_bhist(const int* __restrict__ dsts,
                                               int* __restrict__ counts) {
  __shared__ int hist[NBUK];
  for (int i = threadIdx.x; i < NBUK; i += 256) hist[i] = 0;
  __syncthreads();
  int e0 = blockIdx.x * CHUNK;
  int n = min(CHUNK, N_EDGES - e0);
  for (int i = threadIdx.x; i < n; i += 256)
    atomicAdd(&hist[dsts[e0 + i] >> 8], 1);
  __syncthreads();
  for (int i = threadIdx.x; i < NBUK; i += 256)
    counts[blockIdx.x * NBUK + i] = hist[i];  // chunk-major
}

// A2a: per-bucket exclusive prefix over chunks (one wave per bucket) + total
__global__ __launch_bounds__(64) void k_bscanA(int* __restrict__ counts,
                                               int* __restrict__ tot) {
  int b = blockIdx.x;
  int lane = threadIdx.x;
  int carry = 0;
  for (int c0 = 0; c0 < NCHUNK; c0 += 64) {
    int c = c0 + lane;
    int v = (c < NCHUNK) ? counts[c * NBUK + b] : 0;
    int s = v;
#pragma unroll
    for (int o = 1; o < 64; o <<= 1) {
      int u = __shfl_up(s, o, 64);
      if (lane >= o) s += u;
    }
    if (c < NCHUNK) counts[c * NBUK + b] = s - v + carry;  // bucket-local base
    carry += __shfl(s, 63, 64);
  }
  if (lane == 0) tot[b] = carry;
}

// A2b: scan bucket totals -> bbase
__global__ void k_bscanB(const int* __restrict__ tot, int* __restrict__ bbase) {
  __shared__ int s[512];
  int t = threadIdx.x;
  int v = (t < NBUK) ? tot[t] : 0;
  s[t] = v;
  __syncthreads();
  for (int o = 1; o < 512; o <<= 1) {
    int u = (t >= o) ? s[t - o] : 0;
    __syncthreads();
    s[t] += u;
    __syncthreads();
  }
  if (t <= NBUK) bbase[t] = s[t] - v;  // v==0 for t==NBUK -> total
}

// A2c: add bucket global base into per-chunk bases (coalesced)
__global__ void k_bscanC(int* __restrict__ counts, const int* __restrict__ bbase) {
  int t = threadIdx.x;
  if (t < NBUK) counts[blockIdx.x * NBUK + t] += bbase[t];
}

// A3: rank-scatter packed (src<<8 | dst&255) into bucket-grouped list
__global__ __launch_bounds__(256) void k_bscat(const int* __restrict__ srcs,
                                               const int* __restrict__ dsts,
                                               const int* __restrict__ counts,
                                               unsigned* __restrict__ blist) {
  __shared__ int cnt[NBUK];
  for (int i = threadIdx.x; i < NBUK; i += 256)
    cnt[i] = counts[blockIdx.x * NBUK + i];
  __syncthreads();
  int e0 = blockIdx.x * CHUNK;
  int n = min(CHUNK, N_EDGES - e0);
  for (int i = threadIdx.x; i < n; i += 256) {
    int s = srcs[e0 + i];
    int d = dsts[e0 + i];
    int p = atomicAdd(&cnt[d >> 8], 1);
    blist[p] = ((unsigned)s << 8) | (unsigned)(d & 255);
  }
}

// B: fused per-bucket degree + scan + offset write + csr fill.
__global__ __launch_bounds__(256) void k_bfinal(const unsigned* __restrict__ blist,
                                                const int* __restrict__ bbase,
                                                int* __restrict__ off,
                                                int* __restrict__ csr) {
  __shared__ int hcnt[NPB];
  __shared__ int sc[NPB];
  int t = threadIdx.x;
  int b = blockIdx.x;
  int s = bbase[b], e = bbase[b + 1];
  hcnt[t] = 0;
  __syncthreads();
  for (int i = s + t; i < e; i += 256)
    atomicAdd(&hcnt[blist[i] & 255], 1);
  __syncthreads();
  int v = hcnt[t];
  sc[t] = v;
  __syncthreads();
  for (int o = 1; o < 256; o <<= 1) {
    int u = (t >= o) ? sc[t - o] : 0;
    __syncthreads();
    sc[t] += u;
    __syncthreads();
  }
  int my = s + sc[t] - v;  // global csr offset of this node
  int node = b * NPB + t;
  if (node < N_NODES) off[node] = my;
  if (b == 0 && t == 0) off[N_NODES] = bbase[NBUK];
  sc[t] = my;  // becomes the scatter cursor
  __syncthreads();
  for (int i = s + t; i < e; i += 256) {
    unsigned u = blist[i];
    int p = atomicAdd(&sc[u & 255], 1);
    csr[p] = (int)(u >> 8);
  }
}

// ---------------- K,V projection: wave per row, packed Wk|Wv weights ----------------
// (fallback path, small workspace)

__global__ __launch_bounds__(256) void k_gemmkv(
    const unsigned short* __restrict__ hin,
    const unsigned* __restrict__ PKV,  // lo=Wk, hi=Wv, [k*64+lane]
    const unsigned short* __restrict__ bk, const unsigned short* __restrict__ bv,
    unsigned short* __restrict__ Kt, unsigned short* __restrict__ Vt) {
  int r = blockIdx.x * 4 + (threadIdx.x >> 6);
  int lane = threadIdx.x & 63;
  float hv = bf2f(hin[(size_t)r * 64 + lane]);
  float ka = bf2f(bk[lane]);
  float va = bf2f(bv[lane]);
  for (int k = 0; k < 64; ++k) {
    float hk = __shfl(hv, k, 64);
    unsigned u = PKV[k * 64 + lane];
    ka += hk * lo16(u);
    va += hk * hi16(u);
  }
  Kt[(size_t)r * 64 + lane] = f2bf(ka);
  Vt[(size_t)r * 64 + lane] = f2bf(va);
}

// ---------------- fused K,V,Q,S projection (big-workspace path) ----------------
// Same pass over h computes all four projections; Q,S stored f32 (bit-identical
// accumulation order to the in-edge-kernel projection it replaces).

__global__ __launch_bounds__(256) void k_gemmkvqs(
    const unsigned short* __restrict__ hin,
    const unsigned* __restrict__ PKV, const unsigned* __restrict__ PQS,
    const unsigned short* __restrict__ bk, const unsigned short* __restrict__ bv,
    const unsigned short* __restrict__ bq, const unsigned short* __restrict__ bs,
    unsigned short* __restrict__ Kt, unsigned short* __restrict__ Vt,
    float* __restrict__ Qt, float* __restrict__ St) {
  int r = blockIdx.x * 4 + (threadIdx.x >> 6);
  int lane = threadIdx.x & 63;
  float hv = bf2f(hin[(size_t)r * 64 + lane]);
  float ka = bf2f(bk[lane]);
  float va = bf2f(bv[lane]);
  float qa = bf2f(bq[lane]);
  float sa = bf2f(bs[lane]);
  for (int k = 0; k < 64; ++k) {
    float hk = __shfl(hv, k, 64);
    unsigned u = PKV[k * 64 + lane];
    unsigned u2 = PQS[k * 64 + lane];
    ka += hk * lo16(u);
    va += hk * hi16(u);
    qa += hk * lo16(u2);
    sa += hk * hi16(u2);
  }
  Kt[(size_t)r * 64 + lane] = f2bf(ka);
  Vt[(size_t)r * 64 + lane] = f2bf(va);
  Qt[(size_t)r * 64 + lane] = qa;
  St[(size_t)r * 64 + lane] = sa;
}

// ---------------- edge pass, C=64 (fallback: projection in-kernel) ----------------
// Best measured small-ws config: 250 µs @ 68 VGPR. Do NOT add register
// pressure or min-waves bounds (measured: 92 VGPR -> 289us; forced bounds ->
// 32 VGPR + full spill -> 622us).

template <bool RES>
__global__ __launch_bounds__(256) void k_edge64(
    const int* __restrict__ off, const int* __restrict__ csr,
    const unsigned short* __restrict__ hin,
    const unsigned* __restrict__ PQS,  // lo=Wq, hi=Ws, [k*64+lane]
    const unsigned short* __restrict__ bq, const unsigned short* __restrict__ bs,
    const unsigned short* __restrict__ Kt, const unsigned short* __restrict__ Vt,
    unsigned short* __restrict__ hout) {
  __shared__ float qs[4][64];
  int w = threadIdx.x >> 6;
  int lane = threadIdx.x & 63;
  int wid = blockIdx.x * 4 + w;
  int base = off[wid];
  int deg = off[wid + 1] - base;
  int nsrc = csr[base + ((lane < deg) ? lane : 0)];
  float hv = bf2f(hin[(size_t)wid * 64 + lane]);
  float q = bf2f(bq[lane]);
  float sk = bf2f(bs[lane]);
  for (int k = 0; k < 64; ++k) {
    float hk = __shfl(hv, k, 64);
    unsigned uw = PQS[k * 64 + lane];
    q += hk * lo16(uw);
    sk += hk * hi16(uw);
  }
  qs[w][lane] = q;

  float m = -1e30f, ssum = 0.f;
  float4 acc = {0.f, 0.f, 0.f, 0.f};
  int g = lane >> 4;
  int c16 = lane & 15;
  const float4* qv = (const float4*)qs[w];

  for (int j0 = 0; j0 < deg; j0 += 64) {
    int cnt = min(64, deg - j0);
    int src = nsrc;
    int nj = j0 + 64;
    if (nj < deg)
      nsrc = csr[base + nj + ((lane < deg - nj) ? lane : 0)];
    const uint4* kp = (const uint4*)(Kt + (size_t)src * 64);
    float d0 = 0.f, d1 = 0.f, d2 = 0.f, d3 = 0.f;
#pragma unroll
    for (int i = 0; i < 8; ++i) {
      uint4 kk = kp[i];
      float4 qa = qv[2 * i];
      float4 qb = qv[2 * i + 1];
      d0 += qa.x * lo16(kk.x); d1 += qa.y * hi16(kk.x);
      d2 += qa.z * lo16(kk.y); d3 += qa.w * hi16(kk.y);
      d0 += qb.x * lo16(kk.z); d1 += qb.y * hi16(kk.z);
      d2 += qb.z * lo16(kk.w); d3 += qb.w * hi16(kk.w);
    }
    float sc = ((d0 + d1) + (d2 + d3)) * 0.125f;
    sc = fminf(fmaxf(sc, -60.f), 60.f);
    if (lane >= cnt) sc = -1e30f;
    float bm = sc;
    bm = fmaxf(bm, __shfl_xor(bm, 32, 64));
    bm = fmaxf(bm, __shfl_xor(bm, 16, 64));
    bm = fmaxf(bm, __shfl_xor(bm, 8, 64));
    bm = fmaxf(bm, __shfl_xor(bm, 4, 64));
    bm = fmaxf(bm, __shfl_xor(bm, 2, 64));
    bm = fmaxf(bm, __shfl_xor(bm, 1, 64));
    float mn = fmaxf(m, bm);
    float al = __expf(sc - mn);
    float bsum = al;
    bsum += __shfl_xor(bsum, 32, 64);
    bsum += __shfl_xor(bsum, 16, 64);
    bsum += __shfl_xor(bsum, 8, 64);
    bsum += __shfl_xor(bsum, 4, 64);
    bsum += __shfl_xor(bsum, 2, 64);
    bsum += __shfl_xor(bsum, 1, 64);
    float corr = __expf(m - mn);
    ssum = ssum * corr + bsum;
    acc.x *= corr;
    acc.y *= corr;
    acc.z *= corr;
    acc.w *= corr;
    m = mn;
    for (int jj = 0; jj < cnt; jj += 16) {
      int e0 = jj + g, e1 = jj + 4 + g, e2 = jj + 8 + g, e3 = jj + 12 + g;
      int s0 = __shfl(src, e0, 64);
      int s1 = __shfl(src, e1, 64);
      int s2 = __shfl(src, e2, 64);
      int s3 = __shfl(src, e3, 64);
      float a0 = __shfl(al, e0, 64);
      float a1 = __shfl(al, e1, 64);
      float a2 = __shfl(al, e2, 64);
      float a3 = __shfl(al, e3, 64);
      uint2 v0 = *(const uint2*)(Vt + (size_t)s0 * 64 + c16 * 4);
      uint2 v1 = *(const uint2*)(Vt + (size_t)s1 * 64 + c16 * 4);
      uint2 v2 = *(const uint2*)(Vt + (size_t)s2 * 64 + c16 * 4);
      uint2 v3 = *(const uint2*)(Vt + (size_t)s3 * 64 + c16 * 4);
      acc.x += a0 * lo16(v0.x); acc.y += a0 * hi16(v0.x);
      acc.z += a0 * lo16(v0.y); acc.w += a0 * hi16(v0.y);
      acc.x += a1 * lo16(v1.x); acc.y += a1 * hi16(v1.x);
      acc.z += a1 * lo16(v1.y); acc.w += a1 * hi16(v1.y);
      acc.x += a2 * lo16(v2.x); acc.y += a2 * hi16(v2.x);
      acc.z += a2 * lo16(v2.y); acc.w += a2 * hi16(v2.y);
      acc.x += a3 * lo16(v3.x); acc.y += a3 * hi16(v3.x);
      acc.z += a3 * lo16(v3.y); acc.w += a3 * hi16(v3.y);
    }
  }
  acc.x += __shfl_xor(acc.x, 16, 64);
  acc.y += __shfl_xor(acc.y, 16, 64);
  acc.z += __shfl_xor(acc.z, 16, 64);
  acc.w += __shfl_xor(acc.w, 16, 64);
  acc.x += __shfl_xor(acc.x, 32, 64);
  acc.y += __shfl_xor(acc.y, 32, 64);
  acc.z += __shfl_xor(acc.z, 32, 64);
  acc.w += __shfl_xor(acc.w, 32, 64);
  float f0 = __shfl(acc.x, lane >> 2, 64);
  float f1 = __shfl(acc.y, lane >> 2, 64);
  float f2 = __shfl(acc.z, lane >> 2, 64);
  float f3 = __shfl(acc.w, lane >> 2, 64);
  int cc = lane & 3;
  float aggv = (cc == 0) ? f0 : ((cc == 1) ? f1 : ((cc == 2) ? f2 : f3));
  float val = aggv / (ssum + 1e-16f) + sk;
  if (RES) val += hv;
  hout[(size_t)wid * 64 + lane] = f2bf(tanhf(val));
}

// ---------------- edge pass, C=64, big-ws: projection precomputed ----------------
// Pure attention: q/sk/hv are 3 coalesced loads; no 64-iter loop -> ~40% fewer
// instructions, less VGPR state, shorter per-wave critical path.

template <bool RES>
__global__ __launch_bounds__(256) void k_edge64b(
    const int* __restrict__ off, const int* __restrict__ csr,
    const unsigned short* __restrict__ hin,
    const float* __restrict__ Qt, const float* __restrict__ St,
    const unsigned short* __restrict__ Kt, const unsigned short* __restrict__ Vt,
    unsigned short* __restrict__ hout) {
  __shared__ float qs[4][64];
  int w = threadIdx.x >> 6;
  int lane = threadIdx.x & 63;
  int wid = blockIdx.x * 4 + w;
  int base = off[wid];
  int deg = off[wid + 1] - base;
  int nsrc = csr[base + ((lane < deg) ? lane : 0)];
  float q = Qt[(size_t)wid * 64 + lane];
  float sk = St[(size_t)wid * 64 + lane];
  float hv = 0.f;
  if (RES) hv = bf2f(hin[(size_t)wid * 64 + lane]);
  qs[w][lane] = q;  // wave-local write->read; lgkmcnt ordering within wave

  float m = -1e30f, ssum = 0.f;
  float4 acc = {0.f, 0.f, 0.f, 0.f};
  int g = lane >> 4;
  int c16 = lane & 15;
  const float4* qv = (const float4*)qs[w];

  for (int j0 = 0; j0 < deg; j0 += 64) {
    int cnt = min(64, deg - j0);
    int src = nsrc;
    int nj = j0 + 64;
    if (nj < deg)
      nsrc = csr[base + nj + ((lane < deg - nj) ? lane : 0)];
    const uint4* kp = (const uint4*)(Kt + (size_t)src * 64);
    float d0 = 0.f, d1 = 0.f, d2 = 0.f, d3 = 0.f;
#pragma unroll
    for (int i = 0; i < 8; ++i) {
      uint4 kk = kp[i];
      float4 qa = qv[2 * i];
      float4 qb = qv[2 * i + 1];
      d0 += qa.x * lo16(kk.x); d1 += qa.y * hi16(kk.x);
      d2 += qa.z * lo16(kk.y); d3 += qa.w * hi16(kk.y);
      d0 += qb.x * lo16(kk.z); d1 += qb.y * hi16(kk.z);
      d2 += qb.z * lo16(kk.w); d3 += qb.w * hi16(kk.w);
    }
    float sc = ((d0 + d1) + (d2 + d3)) * 0.125f;
    sc = fminf(fmaxf(sc, -60.f), 60.f);
    if (lane >= cnt) sc = -1e30f;
    float bm = sc;
    bm = fmaxf(bm, __shfl_xor(bm, 32, 64));
    bm = fmaxf(bm, __shfl_xor(bm, 16, 64));
    bm = fmaxf(bm, __shfl_xor(bm, 8, 64));
    bm = fmaxf(bm, __shfl_xor(bm, 4, 64));
    bm = fmaxf(bm, __shfl_xor(bm, 2, 64));
    bm = fmaxf(bm, __shfl_xor(bm, 1, 64));
    float mn = fmaxf(m, bm);
    float al = __expf(sc - mn);
    float bsum = al;
    bsum += __shfl_xor(bsum, 32, 64);
    bsum += __shfl_xor(bsum, 16, 64);
    bsum += __shfl_xor(bsum, 8, 64);
    bsum += __shfl_xor(bsum, 4, 64);
    bsum += __shfl_xor(bsum, 2, 64);
    bsum += __shfl_xor(bsum, 1, 64);
    float corr = __expf(m - mn);
    ssum = ssum * corr + bsum;
    acc.x *= corr;
    acc.y *= corr;
    acc.z *= corr;
    acc.w *= corr;
    m = mn;
    for (int jj = 0; jj < cnt; jj += 16) {
      int e0 = jj + g, e1 = jj + 4 + g, e2 = jj + 8 + g, e3 = jj + 12 + g;
      int s0 = __shfl(src, e0, 64);
      int s1 = __shfl(src, e1, 64);
      int s2 = __shfl(src, e2, 64);
      int s3 = __shfl(src, e3, 64);
      float a0 = __shfl(al, e0, 64);
      float a1 = __shfl(al, e1, 64);
      float a2 = __shfl(al, e2, 64);
      float a3 = __shfl(al, e3, 64);
      uint2 v0 = *(const uint2*)(Vt + (size_t)s0 * 64 + c16 * 4);
      uint2 v1 = *(const uint2*)(Vt + (size_t)s1 * 64 + c16 * 4);
      uint2 v2 = *(const uint2*)(Vt + (size_t)s2 * 64 + c16 * 4);
      uint2 v3 = *(const uint2*)(Vt + (size_t)s3 * 64 + c16 * 4);
      acc.x += a0 * lo16(v0.x); acc.y += a0 * hi16(v0.x);
      acc.z += a0 * lo16(v0.y); acc.w += a0 * hi16(v0.y);
      acc.x += a1 * lo16(v1.x); acc.y += a1 * hi16(v1.x);
      acc.z += a1 * lo16(v1.y); acc.w += a1 * hi16(v1.y);
      acc.x += a2 * lo16(v2.x); acc.y += a2 * hi16(v2.x);
      acc.z += a2 * lo16(v2.y); acc.w += a2 * hi16(v2.y);
      acc.x += a3 * lo16(v3.x); acc.y += a3 * hi16(v3.x);
      acc.z += a3 * lo16(v3.y); acc.w += a3 * hi16(v3.y);
    }
  }
  acc.x += __shfl_xor(acc.x, 16, 64);
  acc.y += __shfl_xor(acc.y, 16, 64);
  acc.z += __shfl_xor(acc.z, 16, 64);
  acc.w += __shfl_xor(acc.w, 16, 64);
  acc.x += __shfl_xor(acc.x, 32, 64);
  acc.y += __shfl_xor(acc.y, 32, 64);
  acc.z += __shfl_xor(acc.z, 32, 64);
  acc.w += __shfl_xor(acc.w, 32, 64);
  float f0 = __shfl(acc.x, lane >> 2, 64);
  float f1 = __shfl(acc.y, lane >> 2, 64);
  float f2 = __shfl(acc.z, lane >> 2, 64);
  float f3 = __shfl(acc.w, lane >> 2, 64);
  int cc = lane & 3;
  float aggv = (cc == 0) ? f0 : ((cc == 1) ? f1 : ((cc == 2) ? f2 : f3));
  float val = aggv / (ssum + 1e-16f) + sk;
  if (RES) val += hv;
  hout[(size_t)wid * 64 + lane] = f2bf(tanhf(val));
}

// ---------------- layer 3 projections (C=3): wave per node ----------------

__global__ __launch_bounds__(256) void k_gemm3(
    const unsigned short* __restrict__ hin,
    const unsigned short* __restrict__ Wq, const unsigned short* __restrict__ bq,
    const unsigned short* __restrict__ Wk, const unsigned short* __restrict__ bk,
    const unsigned short* __restrict__ Wv, const unsigned short* __restrict__ bv,
    const unsigned short* __restrict__ Ws, const unsigned short* __restrict__ bs,
    float* __restrict__ Q3, float* __restrict__ S3, uint4* __restrict__ KV3) {
  int r = blockIdx.x * 4 + (threadIdx.x >> 6);
  int lane = threadIdx.x & 63;
  float hj = bf2f(hin[(size_t)r * 64 + lane]);
  float p[12];
#pragma unroll
  for (int c = 0; c < 3; ++c) {
    p[c]     = hj * bf2f(Wq[lane * 3 + c]);
    p[3 + c] = hj * bf2f(Wk[lane * 3 + c]);
    p[6 + c] = hj * bf2f(Wv[lane * 3 + c]);
    p[9 + c] = hj * bf2f(Ws[lane * 3 + c]);
  }
#pragma unroll
  for (int o = 32; o >= 1; o >>= 1) {
#pragma unroll
    for (int i = 0; i < 12; ++i) p[i] += __shfl_xor(p[i], o, 64);
  }
  if (lane == 0) {
    float kk[3], vv[3];
    for (int c = 0; c < 3; ++c) {
      Q3[r * 4 + c] = p[c] + bf2f(bq[c]);
      S3[r * 4 + c] = p[9 + c] + bf2f(bs[c]);
      kk[c] = p[3 + c] + bf2f(bk[c]);
      vv[c] = p[6 + c] + bf2f(bv[c]);
    }
    uint4 pk;
    pk.x = (unsigned)f2bf(kk[0]) | ((unsigned)f2bf(vv[0]) << 16);
    pk.y = (unsigned)f2bf(kk[1]) | ((unsigned)f2bf(vv[1]) << 16);
    pk.z = (unsigned)f2bf(kk[2]) | ((unsigned)f2bf(vv[2]) << 16);
    pk.w = 0;
    KV3[r] = pk;
  }
}

// ---------------- edge pass, C=3: wave per dst (lane-per-edge) ----------------

__global__ __launch_bounds__(256) void k_edge3(
    const int* __restrict__ off, const int* __restrict__ csr,
    const float* __restrict__ Q3, const float* __restrict__ S3,
    const uint4* __restrict__ KV3, const void* __restrict__ noise,
    void* __restrict__ out, const int* __restrict__ flag) {
  int w = threadIdx.x >> 6;
  int lane = threadIdx.x & 63;
  int d = blockIdx.x * 4 + w;
  int base = off[d];
  int deg = off[d + 1] - base;
  float q0 = Q3[d * 4], q1 = Q3[d * 4 + 1], q2 = Q3[d * 4 + 2];
  const float isq = 0.57735026919f;  // 1/sqrt(3)
  float m = -1e30f, ssum = 0.f, a0 = 0.f, a1 = 0.f, a2 = 0.f;
  for (int j0 = 0; j0 < deg; j0 += 64) {
    int cnt = min(64, deg - j0);
    int src = csr[base + ((lane < cnt) ? (j0 + lane) : 0)];
    uint4 kv = KV3[src];
    float sc = (q0 * lo16(kv.x) + q1 * lo16(kv.y) + q2 * lo16(kv.z)) * isq;
    sc = fminf(fmaxf(sc, -60.f), 60.f);
    if (lane >= cnt) sc = -1e30f;
    float bm = sc;
#pragma unroll
    for (int o = 32; o >= 1; o >>= 1) bm = fmaxf(bm, __shfl_xor(bm, o, 64));
    float mn = fmaxf(m, bm);
    float al = __expf(sc - mn);  // inactive lanes -> 0
    float p0 = al * hi16(kv.x);
    float p1 = al * hi16(kv.y);
    float p2 = al * hi16(kv.z);
    float bsum = al;
#pragma unroll
    for (int o = 32; o >= 1; o >>= 1) {
      bsum += __shfl_xor(bsum, o, 64);
      p0 += __shfl_xor(p0, o, 64);
      p1 += __shfl_xor(p1, o, 64);
      p2 += __shfl_xor(p2, o, 64);
    }
    float corr = __expf(m - mn);
    ssum = ssum * corr + bsum;
    a0 = a0 * corr + p0;
    a1 = a1 * corr + p1;
    a2 = a2 * corr + p2;
    m = mn;
  }
  if (lane == 0) {
    float inv = 1.f / (ssum + 1e-16f);
    int isbf = *flag;
    float n0, n1, n2;
    if (isbf) {
      const unsigned short* nu = (const unsigned short*)noise;
      n0 = bf2f(nu[d * 3 + 0]);
      n1 = bf2f(nu[d * 3 + 1]);
      n2 = bf2f(nu[d * 3 + 2]);
    } else {
      const float* nf = (const float*)noise;
      n0 = nf[d * 3 + 0];
      n1 = nf[d * 3 + 1];
      n2 = nf[d * 3 + 2];
    }
    float r0 = a0 * inv + S3[d * 4 + 0] + 0.1f * n0;
    float r1 = a1 * inv + S3[d * 4 + 1] + 0.1f * n1;
    float r2 = a2 * inv + S3[d * 4 + 2] + 0.1f * n2;
    if (isbf) {
      unsigned short* ou = (unsigned short*)out;
      ou[d * 3 + 0] = f2bf(r0);
      ou[d * 3 + 1] = f2bf(r1);
      ou[d * 3 + 2] = f2bf(r2);
    } else {
      float* of = (float*)out;
      of[d * 3 + 0] = r0;
      of[d * 3 + 1] = r1;
      of[d * 3 + 2] = r2;
    }
  }
}

// ---------------- launch ----------------

extern "C" void kernel_launch(void* const* d_in, const int* in_sizes, int n_in,
                              void* d_out, int out_size, void* d_ws, size_t ws_size,
                              hipStream_t stream) {
  const int* ei = (const int*)d_in[1];
  const int* srcs = ei;
  const int* dsts = ei + N_EDGES;

  // Workspace base layout (NEED = 51668480 B, proven available):
  //   off @0 | csr @400128 | h @13200128 (bf16; CSR-build scratch aliased)
  //   kvbase @26000128: blist during build; then Kt/Vt bf16; Q3/S3/KV3 layer 3
  //   wb @51600128 | flag @51668352
  // Extended layout (if ws_size >= NEED_BIG = 102868480):
  //   Qt f32 [N][64] @51668480 (25.6MB) | St f32 @77268480 (25.6MB)
  char* w = (char*)d_ws;
  int* off = (int*)w;
  int* csr = (int*)(w + 400128);
  char* hreg = w + 13200128;
  unsigned short* h = (unsigned short*)hreg;
  int* counts = (int*)(hreg + 524288);   // NCHUNK*NBUK ints = 611,524 B
  int* bbase = (int*)(hreg + 1200128);   // NBUK+1 ints
  int* tot = (int*)(hreg + 1310720);     // NBUK ints
  char* kvbase = w + 26000128;
  unsigned* blist = (unsigned*)kvbase;
  unsigned short* Kt = (unsigned short*)kvbase;
  unsigned short* Vt = (unsigned short*)(kvbase + 12800000);
  float* Q3 = (float*)kvbase;
  float* S3 = (float*)(kvbase + 2097152);
  uint4* KV3 = (uint4*)(kvbase + 4194304);
  unsigned short* wb = (unsigned short*)(w + 51600128);
  int* flag = (int*)(w + 51668352);
  float* Qt = (float*)(w + 51668480);
  float* St = (float*)(w + 77268480);
  const size_t NEED = 51668480;
  const size_t NEED_BIG = 102868480;
  if (ws_size < NEED) return;
  const bool big = (ws_size >= NEED_BIG);

  CvtArgs ca;
  {
    int idx = 0;
    const int moff[4] = {0, 8192, 8193, 1};  // q,k,v,s matrix dst offsets (shorts)
    const int boff[4] = {16384, 16448, 16512, 16576};
    for (int l = 0; l < 2; ++l) {
      int base = l * 16640;
      for (int p = 0; p < 4; ++p) {
        ca.src[idx] = d_in[3 + l * 8 + p * 2];
        ca.dstoff[idx] = base + moff[p];
        ca.n[idx] = 4096;
        ca.stride[idx] = 2;
        idx++;
        ca.src[idx] = d_in[3 + l * 8 + p * 2 + 1];
        ca.dstoff[idx] = base + boff[p];
        ca.n[idx] = 64;
        ca.stride[idx] = 1;
        idx++;
      }
    }
    int o = 33280;  // layer 3, stride-1
    for (int p = 0; p < 4; ++p) {
      ca.src[idx] = d_in[3 + 16 + p * 2];
      ca.dstoff[idx] = o;
      ca.n[idx] = 192;
      ca.stride[idx] = 1;
      o += 192;
      idx++;
      ca.src[idx] = d_in[3 + 16 + p * 2 + 1];
      ca.dstoff[idx] = o;
      ca.n[idx] = 3;
      ca.stride[idx] = 1;
      o += 3;
      idx++;
    }
  }
  const unsigned* PQS0 = (const unsigned*)(wb);
  const unsigned* PKV0 = (const unsigned*)(wb + 8192);
  const unsigned* PQS1 = (const unsigned*)(wb + 16640);
  const unsigned* PKV1 = (const unsigned*)(wb + 16640 + 8192);
  const unsigned short* Bq0 = wb + 16384;
  const unsigned short* Bk0 = wb + 16448;
  const unsigned short* Bv0 = wb + 16512;
  const unsigned short* Bs0 = wb + 16576;
  const unsigned short* Bq1 = wb + 16640 + 16384;
  const unsigned short* Bk1 = wb + 16640 + 16448;
  const unsigned short* Bv1 = wb + 16640 + 16512;
  const unsigned short* Bs1 = wb + 16640 + 16576;
  const unsigned short* W3q = wb + 33280;
  const unsigned short* B3q = wb + 33472;
  const unsigned short* W3k = wb + 33475;
  const unsigned short* B3k = wb + 33667;
  const unsigned short* W3v = wb + 33670;
  const unsigned short* B3v = wb + 33862;
  const unsigned short* W3s = wb + 33865;
  const unsigned short* B3s = wb + 34057;

  k_detect<<<1, 256, 0, stream>>>((const unsigned short*)d_in[0], flag);
  k_cvt_w<<<24, 256, 0, stream>>>(ca, wb, flag);

  // CSR build (uses hreg + kvbase as scratch; must precede k_cvt_x)
  k_bhist<<<NCHUNK, 256, 0, stream>>>(dsts, counts);
  k_bscanA<<<NBUK, 64, 0, stream>>>(counts, tot);
  k_bscanB<<<1, 512, 0, stream>>>(tot, bbase);
  k_bscanC<<<NCHUNK, 512, 0, stream>>>(counts, bbase);
  k_bscat<<<NCHUNK, 256, 0, stream>>>(srcs, dsts, counts, blist);
  k_bfinal<<<NBUK, 256, 0, stream>>>(blist, bbase, off, csr);

  k_cvt_x<<<N_NODES * 8 / 256, 256, 0, stream>>>(d_in[0], h, flag);

  const int gw = N_NODES / 4;  // 25000 blocks x 4 waves
  if (big) {
    // layer 1
    k_gemmkvqs<<<gw, 256, 0, stream>>>(h, PKV0, PQS0, Bk0, Bv0, Bq0, Bs0,
                                       Kt, Vt, Qt, St);
    k_edge64b<false><<<gw, 256, 0, stream>>>(off, csr, h, Qt, St, Kt, Vt, h);
    // layer 2
    k_gemmkvqs<<<gw, 256, 0, stream>>>(h, PKV1, PQS1, Bk1, Bv1, Bq1, Bs1,
                                       Kt, Vt, Qt, St);
    k_edge64b<true><<<gw, 256, 0, stream>>>(off, csr, h, Qt, St, Kt, Vt, h);
  } else {
    // layer 1
    k_gemmkv<<<gw, 256, 0, stream>>>(h, PKV0, Bk0, Bv0, Kt, Vt);
    k_edge64<false><<<gw, 256, 0, stream>>>(off, csr, h, PQS0, Bq0, Bs0, Kt, Vt, h);
    // layer 2
    k_gemmkv<<<gw, 256, 0, stream>>>(h, PKV1, Bk1, Bv1, Kt, Vt);
    k_edge64<true><<<gw, 256, 0, stream>>>(off, csr, h, PQS1, Bq1, Bs1, Kt, Vt, h);
  }
  // layer 3
  k_gemm3<<<gw, 256, 0, stream>>>(h, W3q, B3q, W3k, B3k, W3v, B3v, W3s, B3s,
                                  Q3, S3, KV3);
  k_edge3<<<gw, 256, 0, stream>>>(off, csr, Q3, S3, KV3, d_in[2], d_out, flag);
}